// Round 2
// baseline (1066.010 us; speedup 1.0000x reference)
//
#include <hip/hip_runtime.h>

#define N_   16
#define M_   8192
#define E_   768
#define Q_   384
#define KC_  24      // 768/32 K-chunks
#define CT_  25      // 24 Wk col-tiles + 1 extra tile (Wcd0, Wcd1, wkq, 0...)

using f32x4  = __attribute__((ext_vector_type(4))) float;
using short8 = __attribute__((ext_vector_type(8))) short;

// ---------- ws layout (bytes) ----------
constexpr size_t OFF_BSWZ = 0;         // 24*24*512 bf16 = 589824
constexpr size_t OFF_BEXT = 589824;    // 16*24*512 bf16 = 393216
constexpr size_t OFF_ATTN = 983040;    // 16*8192 f32 = 524288
constexpr size_t OFF_IMP  = 1507328;   // 524288
constexpr size_t OFF_RETR = 2031616;   // 524288
constexpr size_t OFF_Q    = 2555904;   // 16*384 f32 = 24576
constexpr size_t OFF_WKQ  = 2580480;   // 16*768 f32 = 49152
constexpr size_t OFF_XBAR = 2629632;   // 16*768 f32 = 49152
constexpr size_t OFF_POOL = 2678784;   // 24576
constexpr size_t OFF_HLN  = 2703360;   // 24576
constexpr size_t OFF_H1   = 2727936;   // 16*1536 f32 = 98304
constexpr size_t OFF_QN   = 2826240;   // 16 f32
constexpr size_t OFF_BKQ  = 2826304;   // 16 f32

static __device__ __forceinline__ unsigned short f2bf(float f) {
  unsigned int u = __float_as_uint(f);
  return (unsigned short)((u + 0x7fffu + ((u >> 16) & 1u)) >> 16);  // RNE
}
static __device__ __forceinline__ unsigned int pack2bf(float a, float b) {
  return (unsigned int)f2bf(a) | ((unsigned int)f2bf(b) << 16);
}
static __device__ __forceinline__ float softplus_f(float x) {
  return fmaxf(x, 0.f) + log1pf(expf(-fabsf(x)));
}
static __device__ __forceinline__ void load_lds16(const void* g, void* s) {
  __builtin_amdgcn_global_load_lds(
      (const __attribute__((address_space(1))) unsigned int*)g,
      (__attribute__((address_space(3))) unsigned int*)s, 16, 0, 0);
}

// ---------------- P1: q = query@Wq + bq, qnorm, bkq = bk.q ----------------
__global__ void k_prep_q(const float* __restrict__ query, const float* __restrict__ Wq,
                         const float* __restrict__ bq, const float* __restrict__ bk,
                         float* __restrict__ q_out, float* __restrict__ qnorm,
                         float* __restrict__ bkq) {
  int n = blockIdx.x, t = threadIdx.x;  // 384 threads
  __shared__ float qs[Q_];
  __shared__ float red[8];
  qs[t] = query[n * Q_ + t];
  __syncthreads();
  float acc = bq[t];
#pragma unroll 4
  for (int i = 0; i < Q_; i++) acc += qs[i] * Wq[i * Q_ + t];
  q_out[n * Q_ + t] = acc;
  int l = t & 63, w = t >> 6;
  float v = acc * acc;
  for (int o = 32; o > 0; o >>= 1) v += __shfl_down(v, o);
  if (l == 0) red[w] = v;
  __syncthreads();
  if (t == 0) { float s = 0; for (int i = 0; i < 6; i++) s += red[i]; qnorm[n] = sqrtf(s); }
  __syncthreads();
  float v2 = acc * bk[t];
  for (int o = 32; o > 0; o >>= 1) v2 += __shfl_down(v2, o);
  if (l == 0) red[w] = v2;
  __syncthreads();
  if (t == 0) { float s = 0; for (int i = 0; i < 6; i++) s += red[i]; bkq[n] = s; }
}

// ---------------- P2: wkq[n,e] = Wk[e,:].q[n] ----------------
__global__ void k_wkq(const float* __restrict__ Wk, const float* __restrict__ q_ws,
                      float* __restrict__ wkq) {
  int n = blockIdx.y, t = threadIdx.x;
  int e = blockIdx.x * 256 + t;
  __shared__ float qs[Q_];
  for (int i = t; i < Q_; i += 256) qs[i] = q_ws[n * Q_ + i];
  __syncthreads();
  const float* wr = Wk + (size_t)e * Q_;
  float acc = 0.f;
#pragma unroll 4
  for (int j = 0; j < Q_; j++) acc += wr[j] * qs[j];
  wkq[n * E_ + e] = acc;
}

// ---------------- P3: Wk -> bf16, MFMA-B-fragment order ----------------
__global__ void k_bswz(const float* __restrict__ Wk, unsigned short* __restrict__ Bswz) {
  int b = blockIdx.x;                  // b = kc*24 + ct
  int kc = b / 24, ct = b % 24;
  int l = threadIdx.x;
  int e0 = kc * 32 + (l >> 4) * 8, col = ct * 16 + (l & 15);
  unsigned short u[8];
#pragma unroll
  for (int j = 0; j < 8; j++) u[j] = f2bf(Wk[(size_t)(e0 + j) * Q_ + col]);
  *(uint4*)(Bswz + ((size_t)b * 64 + l) * 8) = *(uint4*)u;
}

// ---------------- P4: per-n extra B tile (Wcd0, Wcd1, wkq_n, 0..) ----------------
__global__ void k_bext(const float* __restrict__ Wcd, const float* __restrict__ wkq,
                       unsigned short* __restrict__ Bext) {
  int kc = blockIdx.x, n = blockIdx.y, l = threadIdx.x;
  int e0 = kc * 32 + (l >> 4) * 8, col = l & 15;
  unsigned short u[8];
#pragma unroll
  for (int j = 0; j < 8; j++) {
    int e = e0 + j;
    float v = 0.f;
    if (col == 0) v = Wcd[e * 2 + 0];
    else if (col == 1) v = Wcd[e * 2 + 1];
    else if (col == 2) v = wkq[n * E_ + e];
    u[j] = f2bf(v);
  }
  *(uint4*)(Bext + ((size_t)(n * KC_ + kc) * 64 + l) * 8) = *(uint4*)u;
}

// ---------------- G: phase 1 — per-row ||k||^2, k.q, gate logits ----------------
__global__ __launch_bounds__(256, 2) void k_phase1(
    const float* __restrict__ x, const unsigned short* __restrict__ Bswz,
    const unsigned short* __restrict__ Bext, const float* __restrict__ bk,
    const float* __restrict__ bcd, const float* __restrict__ qnorm,
    const float* __restrict__ bkq, float* __restrict__ attn_s, float* __restrict__ imp_s) {
  __shared__ __align__(16) unsigned short ldsA[2][2048];   // 64 rows x 32 e, bf16, swizzled
  __shared__ __align__(16) unsigned short ldsB[2][12800];  // 25 tiles x 512 bf16
  const int bid = blockIdx.x;
  const int n = bid >> 7, chunk = bid & 127;
  const int m0 = chunk * 64;
  const int t = threadIdx.x, w = t >> 6, l = t & 63;
  const size_t xbase = ((size_t)(n * M_ + m0)) * E_;

  f32x4 acc[CT_];
#pragma unroll
  for (int ct = 0; ct < CT_; ct++) acc[ct] = (f32x4){0.f, 0.f, 0.f, 0.f};

  float4 va0, va1;
  auto loadA = [&](int kc) {
    int id0 = t, id1 = t + 256;
    va0 = *(const float4*)(x + xbase + (size_t)(id0 >> 3) * E_ + kc * 32 + (id0 & 7) * 4);
    va1 = *(const float4*)(x + xbase + (size_t)(id1 >> 3) * E_ + kc * 32 + (id1 & 7) * 4);
  };
  auto writeA = [&](int buf) {
    {
      int row = t >> 3, c4 = t & 7;
      int byte = (row * 64 + c4 * 8) ^ ((row & 7) << 4);
      uint2 p; p.x = pack2bf(va0.x, va0.y); p.y = pack2bf(va0.z, va0.w);
      *(uint2*)((char*)(&ldsA[buf][0]) + byte) = p;
    }
    {
      int id = t + 256;
      int row = id >> 3, c4 = id & 7;
      int byte = (row * 64 + c4 * 8) ^ ((row & 7) << 4);
      uint2 p; p.x = pack2bf(va1.x, va1.y); p.y = pack2bf(va1.z, va1.w);
      *(uint2*)((char*)(&ldsA[buf][0]) + byte) = p;
    }
  };
  auto stageB = [&](int kc, int buf) {
    for (int ct = w; ct < CT_; ct += 4) {
      const unsigned short* src = (ct < 24)
          ? Bswz + ((size_t)(kc * 24 + ct) * 64 + l) * 8
          : Bext + ((size_t)(n * KC_ + kc) * 64 + l) * 8;
      load_lds16(src, &ldsB[buf][ct * 512]);
    }
  };

  loadA(0);
  stageB(0, 0);
  writeA(0);
  __syncthreads();

  const int abyte_base = ((w * 16 + (l & 15)) * 64 + ((l >> 4) * 16)) ^ ((l & 7) << 4);
  for (int kc = 0; kc < KC_; ++kc) {
    int cur = kc & 1;
    if (kc < KC_ - 1) { loadA(kc + 1); stageB(kc + 1, cur ^ 1); }
    short8 a = *(const short8*)((const char*)(&ldsA[cur][0]) + abyte_base);
#pragma unroll
    for (int ct = 0; ct < CT_; ++ct) {
      short8 b = *(const short8*)(&ldsB[cur][ct * 512 + l * 8]);
      acc[ct] = __builtin_amdgcn_mfma_f32_16x16x32_bf16(a, b, acc[ct], 0, 0, 0);
    }
    if (kc < KC_ - 1) writeA(cur ^ 1);
    __syncthreads();
  }

  // epilogue: rows w*16 + (l>>4)*4 + r ; cols (l&15) per tile
  const int colg = l & 15;
  const float bcd0 = bcd[0], bcd1 = bcd[1];
  const float qn = qnorm[n], bqd = bkq[n];
  float bkreg[24];
#pragma unroll
  for (int ct = 0; ct < 24; ct++) bkreg[ct] = bk[ct * 16 + colg];
#pragma unroll
  for (int r = 0; r < 4; r++) {
    float ss = 0.f;
#pragma unroll
    for (int ct = 0; ct < 24; ct++) {
      float kv = acc[ct][r] + bkreg[ct];
      ss += kv * kv;
    }
    ss += __shfl_xor(ss, 1); ss += __shfl_xor(ss, 2);
    ss += __shfl_xor(ss, 4); ss += __shfl_xor(ss, 8);
    float c24 = acc[24][r];
    float c0 = __shfl(c24, 0, 16) + bcd0;
    float c1 = __shfl(c24, 1, 16) + bcd1;
    float dt = __shfl(c24, 2, 16) + bqd;
    float attn = dt / (sqrtf(ss) * qn);
    float u = 2.f * (softplus_f(-c0) - softplus_f(-c1));
    float imp = 1.f / (1.f + expf(-u));
    if (colg == 0) {
      int m = m0 + w * 16 + (l >> 4) * 4 + r;
      attn_s[n * M_ + m] = attn;
      imp_s[n * M_ + m] = imp;
    }
  }
}

// ---------------- softmax(attn) -> relevance -> retrieval ----------------
__global__ void k_soft(const float* __restrict__ attn_s, const float* __restrict__ imp_s,
                       float* __restrict__ retr) {
  int n = blockIdx.x, t = threadIdx.x;  // 256 threads
  __shared__ float red[4];
  int l = t & 63, w = t >> 6;
  float a[32];
  float amax = -1e30f;
#pragma unroll
  for (int i = 0; i < 32; i++) {
    a[i] = attn_s[n * M_ + i * 256 + t];
    amax = fmaxf(amax, a[i]);
  }
  for (int o = 32; o > 0; o >>= 1) amax = fmaxf(amax, __shfl_down(amax, o));
  if (l == 0) red[w] = amax;
  __syncthreads();
  amax = fmaxf(fmaxf(red[0], red[1]), fmaxf(red[2], red[3]));
  __syncthreads();
  float s = 0.f;
#pragma unroll
  for (int i = 0; i < 32; i++) { a[i] = expf(a[i] - amax); s += a[i]; }
  for (int o = 32; o > 0; o >>= 1) s += __shfl_down(s, o);
  if (l == 0) red[w] = s;
  __syncthreads();
  s = red[0] + red[1] + red[2] + red[3];
  __syncthreads();
  float inv = 1.f / s;
  float lmax = -1e30f;
#pragma unroll
  for (int i = 0; i < 32; i++) {
    int m = i * 256 + t;
    float rec = expf((float)(511 - (m & 511)) * -0.0030045090f);  // 0.997^(511-(m&511))
    float z = a[i] * inv + 0.5f * imp_s[n * M_ + m] + 0.2f * rec;
    a[i] = z;
    lmax = fmaxf(lmax, z);
  }
  for (int o = 32; o > 0; o >>= 1) lmax = fmaxf(lmax, __shfl_down(lmax, o));
  if (l == 0) red[w] = lmax;
  __syncthreads();
  lmax = fmaxf(fmaxf(red[0], red[1]), fmaxf(red[2], red[3]));
  __syncthreads();
  float s2 = 0.f;
#pragma unroll
  for (int i = 0; i < 32; i++) { a[i] = expf(a[i] - lmax); s2 += a[i]; }
  for (int o = 32; o > 0; o >>= 1) s2 += __shfl_down(s2, o);
  if (l == 0) red[w] = s2;
  __syncthreads();
  s2 = red[0] + red[1] + red[2] + red[3];
  float inv2 = 1.f / s2;
#pragma unroll
  for (int i = 0; i < 32; i++) retr[n * M_ + i * 256 + t] = a[i] * inv2;
}

// ---------------- xbar[n] = sum_m retr[n,m] * x[n,m,:] ----------------
__global__ __launch_bounds__(256) void k_xbar(const float* __restrict__ x,
                                              const float* __restrict__ retr,
                                              float* __restrict__ xbar) {
  int c = blockIdx.x, n = blockIdx.y, t = threadIdx.x;
  size_t base = ((size_t)n * M_ + (size_t)c * 256) * E_;
  const float* rp = retr + n * M_ + c * 256;
  float a0 = 0.f, a1 = 0.f, a2 = 0.f;
#pragma unroll 4
  for (int r = 0; r < 256; r++) {
    float wgt = rp[r];
    const float* xr = x + base + (size_t)r * E_;
    a0 += wgt * xr[t];
    a1 += wgt * xr[t + 256];
    a2 += wgt * xr[t + 512];
  }
  atomicAdd(&xbar[n * E_ + t], a0);
  atomicAdd(&xbar[n * E_ + t + 256], a1);
  atomicAdd(&xbar[n * E_ + t + 512], a2);
}

// ---------------- pooled = xbar@Wv + bv ; layernorm ----------------
__global__ void k_pool_ln(const float* __restrict__ xbar, const float* __restrict__ Wv,
                          const float* __restrict__ bv, const float* __restrict__ ln_g,
                          const float* __restrict__ ln_b, float* __restrict__ pooled,
                          float* __restrict__ hln) {
  int n = blockIdx.x, t = threadIdx.x;  // 384 threads
  __shared__ float xb[E_];
  __shared__ float red[8];
  for (int i = t; i < E_; i += 384) xb[i] = xbar[n * E_ + i];
  __syncthreads();
  float p = bv[t];
#pragma unroll 4
  for (int e = 0; e < E_; e++) p += xb[e] * Wv[(size_t)e * Q_ + t];
  pooled[n * Q_ + t] = p;
  int l = t & 63, w = t >> 6;
  float v = p;
  for (int o = 32; o > 0; o >>= 1) v += __shfl_down(v, o);
  if (l == 0) red[w] = v;
  __syncthreads();
  float mean = (red[0] + red[1] + red[2] + red[3] + red[4] + red[5]) / (float)Q_;
  __syncthreads();
  float d = p - mean;
  float v2 = d * d;
  for (int o = 32; o > 0; o >>= 1) v2 += __shfl_down(v2, o);
  if (l == 0) red[w] = v2;
  __syncthreads();
  float var = (red[0] + red[1] + red[2] + red[3] + red[4] + red[5]) / (float)Q_;
  hln[n * Q_ + t] = ln_g[t] * d * rsqrtf(var + 1e-6f) + ln_b[t];
}

// ---------------- h1 = gelu(hln@W1 + b1) ----------------
__global__ void k_ffn1(const float* __restrict__ hln, const float* __restrict__ W1,
                       const float* __restrict__ b1, float* __restrict__ h1) {
  int n = blockIdx.y, t = threadIdx.x;
  int j = blockIdx.x * 256 + t;
  __shared__ float hs[Q_];
  for (int i = t; i < Q_; i += 256) hs[i] = hln[n * Q_ + i];
  __syncthreads();
  float acc = b1[j];
#pragma unroll 4
  for (int q = 0; q < Q_; q++) acc += hs[q] * W1[(size_t)q * 1536 + j];
  h1[n * 1536 + j] = 0.5f * acc * (1.f + erff(acc * 0.70710678118654752f));
}

// ---------------- out = pooled + h1@Wmu + bmu ----------------
__global__ void k_ffn2(const float* __restrict__ h1, const float* __restrict__ pooled,
                       const float* __restrict__ Wmu, const float* __restrict__ bmu,
                       float* __restrict__ out) {
  int n = blockIdx.x, t = threadIdx.x;  // 384 threads
  __shared__ float hs[1536];
  for (int i = t; i < 1536; i += 384) hs[i] = h1[n * 1536 + i];
  __syncthreads();
  float acc = bmu[t];
#pragma unroll 4
  for (int j = 0; j < 1536; j++) acc += hs[j] * Wmu[(size_t)j * Q_ + t];
  out[n * Q_ + t] = pooled[n * Q_ + t] + acc;
}

extern "C" void kernel_launch(void* const* d_in, const int* in_sizes, int n_in,
                              void* d_out, int out_size, void* d_ws, size_t ws_size,
                              hipStream_t stream) {
  (void)in_sizes; (void)n_in; (void)out_size; (void)ws_size;
  const float* x     = (const float*)d_in[0];
  const float* query = (const float*)d_in[1];
  const float* Wcd   = (const float*)d_in[2];
  const float* bcd   = (const float*)d_in[3];
  const float* Wk    = (const float*)d_in[4];
  const float* bk    = (const float*)d_in[5];
  const float* Wv    = (const float*)d_in[6];
  const float* bv    = (const float*)d_in[7];
  const float* Wq    = (const float*)d_in[8];
  const float* bq    = (const float*)d_in[9];
  const float* ln_g  = (const float*)d_in[10];
  const float* ln_b  = (const float*)d_in[11];
  const float* W1    = (const float*)d_in[12];
  const float* b1    = (const float*)d_in[13];
  const float* Wmu   = (const float*)d_in[14];
  const float* bmu   = (const float*)d_in[15];
  float* out = (float*)d_out;
  char* ws = (char*)d_ws;

  float* q_ws   = (float*)(ws + OFF_Q);
  float* qn_ws  = (float*)(ws + OFF_QN);
  float* bkq_ws = (float*)(ws + OFF_BKQ);
  float* wkq_ws = (float*)(ws + OFF_WKQ);
  unsigned short* bswz = (unsigned short*)(ws + OFF_BSWZ);
  unsigned short* bext = (unsigned short*)(ws + OFF_BEXT);
  float* attn_ws = (float*)(ws + OFF_ATTN);
  float* imp_ws  = (float*)(ws + OFF_IMP);
  float* retr_ws = (float*)(ws + OFF_RETR);
  float* xbar_ws = (float*)(ws + OFF_XBAR);
  float* pool_ws = (float*)(ws + OFF_POOL);
  float* hln_ws  = (float*)(ws + OFF_HLN);
  float* h1_ws   = (float*)(ws + OFF_H1);

  k_prep_q<<<N_, 384, 0, stream>>>(query, Wq, bq, bk, q_ws, qn_ws, bkq_ws);
  k_wkq<<<dim3(3, N_), 256, 0, stream>>>(Wk, q_ws, wkq_ws);
  k_bswz<<<KC_ * 24, 64, 0, stream>>>(Wk, bswz);
  k_bext<<<dim3(KC_, N_), 64, 0, stream>>>(Wcd, wkq_ws, bext);
  k_phase1<<<N_ * 128, 256, 0, stream>>>(x, bswz, bext, bk, bcd, qn_ws, bkq_ws,
                                         attn_ws, imp_ws);
  k_soft<<<N_, 256, 0, stream>>>(attn_ws, imp_ws, retr_ws);
  hipMemsetAsync(xbar_ws, 0, N_ * E_ * sizeof(float), stream);
  k_xbar<<<dim3(32, N_), 256, 0, stream>>>(x, retr_ws, xbar_ws);
  k_pool_ln<<<N_, 384, 0, stream>>>(xbar_ws, Wv, bv, ln_g, ln_b, pool_ws, hln_ws);
  k_ffn1<<<dim3(6, N_), 256, 0, stream>>>(hln_ws, W1, b1, h1_ws);
  k_ffn2<<<N_, 384, 0, stream>>>(h1_ws, pool_ws, Wmu, bmu, out);
}